// Round 1
// 636.281 us; speedup vs baseline: 1.3046x; 1.3046x over previous
//
#include <hip/hip_runtime.h>
#include <math.h>

#define BLOCK 128   // 2 waves: wave 0 = compute (1 particle/lane), wave 1 = LDS->HBM writer
#define PPB   64    // particles per block
#define TW    16    // timesteps staged per LDS tile

// LDS layout: lds[buf][ (c6*PPB + p)*TW + (tt ^ swz(p)) ], swz(p) = (p>>1)&15.
// swz makes compute-side writes (p varies, tt fixed: bank = 16*(p&1) + (tt^swz) -> all
// 32 banks hit once per 32 lanes) AND writer-side reads conflict-free, while the
// drained global addresses per 16-lane group remain one contiguous (permuted) 64B run.
__global__ __launch_bounds__(BLOCK) void track_rk4(
    const float* __restrict__ r_in,
    const float* __restrict__ d_vec,
    const float* __restrict__ g_in,
    const float* __restrict__ t_in,
    const float* __restrict__ b_in,
    float* __restrict__ out,
    int N, int T)
{
    __shared__ float lds[2][6 * PPB * TW];   // 2 x 24 KiB = 48 KiB

    const int tid    = threadIdx.x;
    const int wid    = tid >> 6;      // 0 = compute wave, 1 = writer wave
    const int lane   = tid & 63;
    const int blockP = blockIdx.x * PPB;

    const long Tl    = (long)T;
    const long boff  = 3L * (long)N * Tl;    // offset to beta block
    const int ntiles = (T + TW - 1) / TW;

    const float c      = 0.299792458f;
    const float c2     = c * c;
    const float inv_c2 = 1.0f / c2;
    const float k_u    = 6.283185307179586f; // 2*pi

    const float b0  = b_in[0];
    const float dt  = t_in[1] - t_in[0];
    const float dt2 = 0.5f * dt;
    const float dt6 = dt * (1.0f / 6.0f);

    // ---- compute-wave particle state (writer wave leaves these dead) ----
    float rx = 0.f, ry = 0.f, rz = 0.f, px = 0.f, py = 0.f, pz = 0.f, py2 = 0.f;
    const int n0 = blockP + lane;
    if (wid == 0 && n0 < N) {
        rx = r_in[3*n0+0]; ry = r_in[3*n0+1]; rz = r_in[3*n0+2];
        const float dx = d_vec[3*n0+0], dy = d_vec[3*n0+1], dz = d_vec[3*n0+2];
        const float g0 = g_in[n0];
        const float pscale = c * sqrtf(g0*g0 - 1.0f)
                           * rsqrtf(fmaf(dx,dx, fmaf(dy,dy, dz*dz)));
        px = dx * pscale; py = dy * pscale; pz = dz * pscale; py2 = py * py;
    }

    const int swz  = (lane >> 1) & 15;  // compute-side swizzle (p == lane)
    const int bofs = lane * TW;         // compute-side particle base

    // writer-lane decomposition: 4 streams x 16 time-elements per store
    const int g = lane >> 4;            // stream within group of 4
    const int e = lane & 15;            // time element within tile

    for (int tile = 0; tile < ntiles; ++tile) {
        if (wid == 0) {
            // ---------------- produce tile into buf[tile&1] ----------------
            float* __restrict__ Lb = lds[tile & 1];
            const int t0 = tile * TW;
            #pragma unroll
            for (int tt = 0; tt < TW; ++tt) {
                const int tg = t0 + tt;
                if (tg < T) {
                    if (tg > 0) {
                        // ---- RK4 step (arithmetic identical to verified kernel)
                        float ig1  = rsqrtf(fmaf(fmaf(px,px, fmaf(pz,pz, py2)), inv_c2, 1.0f));
                        float By1  = b0 * __cosf(k_u * rz);
                        float rk1x = px*ig1, rk1z = pz*ig1;
                        float h1   = By1 * ig1;
                        float pk1x =  pz*h1, pk1z = -px*h1;

                        float p2x = fmaf(pk1x, dt2, px);
                        float p2z = fmaf(pk1z, dt2, pz);
                        float z2  = fmaf(rk1z, dt2, rz);
                        float ig2  = rsqrtf(fmaf(fmaf(p2x,p2x, fmaf(p2z,p2z, py2)), inv_c2, 1.0f));
                        float By2  = b0 * __cosf(k_u * z2);
                        float rk2x = p2x*ig2, rk2z = p2z*ig2;
                        float h2   = By2 * ig2;
                        float pk2x =  p2z*h2, pk2z = -p2x*h2;

                        float p3x = fmaf(pk2x, dt2, px);
                        float p3z = fmaf(pk2z, dt2, pz);
                        float z3  = fmaf(rk2z, dt2, rz);
                        float ig3  = rsqrtf(fmaf(fmaf(p3x,p3x, fmaf(p3z,p3z, py2)), inv_c2, 1.0f));
                        float By3  = b0 * __cosf(k_u * z3);
                        float rk3x = p3x*ig3, rk3z = p3z*ig3;
                        float h3   = By3 * ig3;
                        float pk3x =  p3z*h3, pk3z = -p3x*h3;

                        float p4x = fmaf(pk3x, dt, px);
                        float p4z = fmaf(pk3z, dt, pz);
                        float z4  = fmaf(rk3z, dt, rz);
                        float ig4  = rsqrtf(fmaf(fmaf(p4x,p4x, fmaf(p4z,p4z, py2)), inv_c2, 1.0f));
                        float By4  = b0 * __cosf(k_u * z4);
                        float rk4x = p4x*ig4, rk4z = p4z*ig4;
                        float h4   = By4 * ig4;
                        float pk4x =  p4z*h4, pk4z = -p4x*h4;

                        float igsum = ig1 + 2.0f*ig2 + 2.0f*ig3 + ig4;
                        rx = fmaf(dt6, rk1x + 2.0f*rk2x + 2.0f*rk3x + rk4x, rx);
                        ry = fmaf(dt6, py * igsum, ry);
                        rz = fmaf(dt6, rk1z + 2.0f*rk2z + 2.0f*rk3z + rk4z, rz);
                        px = fmaf(dt6, pk1x + 2.0f*pk2x + 2.0f*pk3x + pk4x, px);
                        pz = fmaf(dt6, pk1z + 2.0f*pk2z + 2.0f*pk3z + pk4z, pz);
                    }
                    const float ib = rsqrtf(fmaf(px,px, fmaf(pz,pz, py2 + c2)));
                    const int o = bofs + (tt ^ swz);
                    Lb[0*(PPB*TW) + o] = rx;
                    Lb[1*(PPB*TW) + o] = ry;
                    Lb[2*(PPB*TW) + o] = rz;
                    Lb[3*(PPB*TW) + o] = px * ib;
                    Lb[4*(PPB*TW) + o] = py * ib;
                    Lb[5*(PPB*TW) + o] = pz * ib;
                }
            }
        } else if (tile > 0) {
            // ---------------- drain tile-1 from buf[(tile-1)&1] ----------------
            const int dtile = tile - 1;
            const float* __restrict__ Lb = lds[dtile & 1];
            const int t0  = dtile * TW;
            const int rem = (T - t0 < TW) ? (T - t0) : TW;
            if (e < rem) {
                #pragma unroll
                for (int c6 = 0; c6 < 6; ++c6) {
                    for (int pb = 0; pb < PPB; pb += 4) {
                        const int p = pb + g;
                        const int n = blockP + p;
                        if (n < N) {
                            const float v = Lb[(c6*PPB + p)*TW + (e ^ ((p >> 1) & 15))];
                            float* __restrict__ bp = (c6 < 3)
                                ? (out + (3L*n + c6) * Tl)
                                : (out + boff + (3L*n + (c6 - 3)) * Tl);
                            bp[t0 + e] = v;  // 16 lanes -> one contiguous 64B run
                        }
                    }
                }
            }
        }
        __syncthreads();   // wave-uniform role branch; both waves hit every barrier
    }

    // ---------------- drain the final tile ----------------
    if (wid == 1) {
        const int dtile = ntiles - 1;
        const float* __restrict__ Lb = lds[dtile & 1];
        const int t0  = dtile * TW;
        const int rem = (T - t0 < TW) ? (T - t0) : TW;
        if (e < rem) {
            #pragma unroll
            for (int c6 = 0; c6 < 6; ++c6) {
                for (int pb = 0; pb < PPB; pb += 4) {
                    const int p = pb + g;
                    const int n = blockP + p;
                    if (n < N) {
                        const float v = Lb[(c6*PPB + p)*TW + (e ^ ((p >> 1) & 15))];
                        float* __restrict__ bp = (c6 < 3)
                            ? (out + (3L*n + c6) * Tl)
                            : (out + boff + (3L*n + (c6 - 3)) * Tl);
                        bp[t0 + e] = v;
                    }
                }
            }
        }
    }
}

extern "C" void kernel_launch(void* const* d_in, const int* in_sizes, int n_in,
                              void* d_out, int out_size, void* d_ws, size_t ws_size,
                              hipStream_t stream) {
    const float* r  = (const float*)d_in[0];
    const float* d  = (const float*)d_in[1];
    const float* g  = (const float*)d_in[2];
    const float* tm = (const float*)d_in[3];
    const float* b0 = (const float*)d_in[4];
    float* out = (float*)d_out;

    const int N = in_sizes[2];   // bunch_gamma has N elements
    const int T = in_sizes[3];   // time has T elements

    const int blocks = (N + PPB - 1) / PPB;
    track_rk4<<<blocks, BLOCK, 0, stream>>>(r, d, g, tm, b0, out, N, T);
}

// Round 2
// 620.556 us; speedup vs baseline: 1.3377x; 1.0253x over previous
//
#include <hip/hip_runtime.h>
#include <math.h>

#define BLOCK 128   // wave 0 = compute (1 particle/lane), wave 1 = LDS->HBM writer
#define PPB   64    // particles per block
#define TW    16    // timesteps per LDS tile
#define ROW   385   // dwords per time-row: 6*64 + 1 (odd stride => conflict-free reads)
#define BUFSZ (TW * ROW)   // 6160 dwords per buffer

// LDS layout: L[buf*BUFSZ + tt*ROW + c6*64 + pi(p)],  pi(p) = ((p&3)<<4)|(p>>2).
//  - compute wave writes 6 floats/step at one vaddr (pi) + immediate offsets
//    (bank = 16*(lane&1) + (lane>>2) -> exactly 2 lanes/bank, free)
//  - writer wave (lane = g*16+e, g=stream-group, e=time): reads
//    L[e*ROW + c6*64 + g*16 + i], i=0..15 CONTIGUOUS dwords -> 16 independent
//    ds_read_b32 batched in flight (bank = e+16g mod 32 -> 2 lanes/bank, free)
//  - global stores: 16 lanes (fixed g) cover 16 consecutive t -> one 64B line
__global__ __launch_bounds__(BLOCK) void track_rk4(
    const float* __restrict__ r_in,
    const float* __restrict__ d_vec,
    const float* __restrict__ g_in,
    const float* __restrict__ t_in,
    const float* __restrict__ b_in,
    float* __restrict__ out,
    int N, int T)
{
    __shared__ float L[2 * BUFSZ];   // 49280 B

    const int tid    = threadIdx.x;
    const int wid    = tid >> 6;
    const int lane   = tid & 63;
    const int blockP = blockIdx.x * PPB;

    const long Tl     = (long)T;
    const long boff   = 3L * (long)N * Tl;
    const int  ntiles = (T + TW - 1) / TW;

    const float c      = 0.299792458f;
    const float c2     = c * c;
    const float inv_c2 = 1.0f / c2;
    const float inv_c  = 1.0f / c;
    const float k_u    = 6.283185307179586f;

    const float b0  = b_in[0];
    const float dt  = t_in[1] - t_in[0];
    const float dt2 = 0.5f * dt;
    const float dt6 = dt * (1.0f / 6.0f);

    if (wid == 0) {
        // ======================= COMPUTE WAVE =======================
        float rx = 0.f, ry = 0.f, rz = 0.f, px = 0.f, py = 0.f, pz = 0.f, py2 = 0.f;
        const int n0 = blockP + lane;
        if (n0 < N) {
            rx = r_in[3*n0+0]; ry = r_in[3*n0+1]; rz = r_in[3*n0+2];
            const float dx = d_vec[3*n0+0], dy = d_vec[3*n0+1], dz = d_vec[3*n0+2];
            const float g0 = g_in[n0];
            const float pscale = c * sqrtf(g0*g0 - 1.0f)
                               * rsqrtf(fmaf(dx,dx, fmaf(dy,dy, dz*dz)));
            px = dx * pscale; py = dy * pscale; pz = dz * pscale; py2 = py * py;
        }

        const int pi = ((lane & 3) << 4) | (lane >> 2);   // particle permutation

        // invariants carried across steps: ig = 1/gamma, By at current state
        float ig = rsqrtf(fmaf(fmaf(px,px, fmaf(pz,pz, py2)), inv_c2, 1.0f));
        float By = b0 * __cosf(k_u * rz);

        for (int tile = 0; tile <= ntiles; ++tile) {
            if (tile < ntiles) {
                float* __restrict__ Lw = &L[(tile & 1) * BUFSZ + pi];
                const int t0 = tile * TW;
                #pragma unroll
                for (int tt = 0; tt < TW; ++tt) {
                    const int tg = t0 + tt;
                    if (tg < T) {
                        if (tg > 0) {
                            // ---- stage 1 (ig, By precomputed -> off critical chain)
                            float rk1x = px*ig, rk1z = pz*ig;
                            float h1   = By * ig;
                            float pk1x =  pz*h1, pk1z = -px*h1;
                            // ---- stage 2
                            float p2x = fmaf(pk1x, dt2, px);
                            float p2z = fmaf(pk1z, dt2, pz);
                            float z2  = fmaf(rk1z, dt2, rz);
                            float ig2  = rsqrtf(fmaf(fmaf(p2x,p2x, fmaf(p2z,p2z, py2)), inv_c2, 1.0f));
                            float By2  = b0 * __cosf(k_u * z2);
                            float rk2x = p2x*ig2, rk2z = p2z*ig2;
                            float h2   = By2 * ig2;
                            float pk2x =  p2z*h2, pk2z = -p2x*h2;
                            // ---- stage 3
                            float p3x = fmaf(pk2x, dt2, px);
                            float p3z = fmaf(pk2z, dt2, pz);
                            float z3  = fmaf(rk2z, dt2, rz);
                            float ig3  = rsqrtf(fmaf(fmaf(p3x,p3x, fmaf(p3z,p3z, py2)), inv_c2, 1.0f));
                            float By3  = b0 * __cosf(k_u * z3);
                            float rk3x = p3x*ig3, rk3z = p3z*ig3;
                            float h3   = By3 * ig3;
                            float pk3x =  p3z*h3, pk3z = -p3x*h3;
                            // ---- stage 4
                            float p4x = fmaf(pk3x, dt, px);
                            float p4z = fmaf(pk3z, dt, pz);
                            float z4  = fmaf(rk3z, dt, rz);
                            float ig4  = rsqrtf(fmaf(fmaf(p4x,p4x, fmaf(p4z,p4z, py2)), inv_c2, 1.0f));
                            float By4  = b0 * __cosf(k_u * z4);
                            float rk4x = p4x*ig4, rk4z = p4z*ig4;
                            float h4   = By4 * ig4;
                            float pk4x =  p4z*h4, pk4z = -p4x*h4;
                            // ---- combine
                            float igsum = ig + 2.0f*ig2 + 2.0f*ig3 + ig4;
                            rx = fmaf(dt6, rk1x + 2.0f*rk2x + 2.0f*rk3x + rk4x, rx);
                            ry = fmaf(dt6, py * igsum, ry);
                            rz = fmaf(dt6, rk1z + 2.0f*rk2z + 2.0f*rk3z + rk4z, rz);
                            px = fmaf(dt6, pk1x + 2.0f*pk2x + 2.0f*pk3x + pk4x, px);
                            pz = fmaf(dt6, pk1z + 2.0f*pk2z + 2.0f*pk3z + pk4z, pz);
                            // ---- refresh invariants (next step's stage 1 + output)
                            ig = rsqrtf(fmaf(fmaf(px,px, fmaf(pz,pz, py2)), inv_c2, 1.0f));
                            By = b0 * __cosf(k_u * rz);
                        }
                        const float ib = ig * inv_c;   // == rsqrt(c2 + |p|^2)
                        Lw[tt*ROW + 0*64] = rx;
                        Lw[tt*ROW + 1*64] = ry;
                        Lw[tt*ROW + 2*64] = rz;
                        Lw[tt*ROW + 3*64] = px * ib;
                        Lw[tt*ROW + 4*64] = py * ib;
                        Lw[tt*ROW + 5*64] = pz * ib;
                    }
                }
            }
            __syncthreads();
        }
    } else {
        // ======================= WRITER WAVE =======================
        const int g = lane >> 4;           // stream group (particle % 4 slot)
        const int e = lane & 15;           // time element within tile
        const int rbase = e * ROW + g * 16;
        const long pstride = 3L * Tl;      // +4 particles => +12*Tl floats

        float* bp[6];
        #pragma unroll
        for (int c6 = 0; c6 < 6; ++c6) {
            const int  c6m = (c6 < 3) ? c6 : c6 - 3;
            const long sel = (c6 < 3) ? 0L : boff;
            bp[c6] = out + sel + (3L*(blockP + g) + c6m) * Tl + e;
        }
        const int pbmax = N - blockP - g;  // store iff pb < pbmax

        for (int tile = 0; tile <= ntiles; ++tile) {
            if (tile > 0) {
                const int dtile = tile - 1;
                const float* __restrict__ Lb = &L[(dtile & 1) * BUFSZ];
                const int t0  = dtile * TW;
                const int rem = (T - t0 < TW) ? (T - t0) : TW;
                const bool on = (e < rem);
                #pragma unroll
                for (int c6 = 0; c6 < 6; ++c6) {
                    float v[16];
                    #pragma unroll
                    for (int i = 0; i < 16; ++i)        // 16 contiguous dwords:
                        v[i] = Lb[rbase + c6*64 + i];   // batched, conflict-free
                    #pragma unroll
                    for (int i = 0; i < 16; ++i) {
                        const int pb = i * 4;
                        if (on && pb < pbmax)
                            bp[c6][(long)t0 + pb * pstride] = v[i];
                    }
                }
            }
            __syncthreads();
        }
    }
}

extern "C" void kernel_launch(void* const* d_in, const int* in_sizes, int n_in,
                              void* d_out, int out_size, void* d_ws, size_t ws_size,
                              hipStream_t stream) {
    const float* r  = (const float*)d_in[0];
    const float* d  = (const float*)d_in[1];
    const float* g  = (const float*)d_in[2];
    const float* tm = (const float*)d_in[3];
    const float* b0 = (const float*)d_in[4];
    float* out = (float*)d_out;

    const int N = in_sizes[2];   // bunch_gamma has N elements
    const int T = in_sizes[3];   // time has T elements

    const int blocks = (N + PPB - 1) / PPB;
    track_rk4<<<blocks, BLOCK, 0, stream>>>(r, d, g, tm, b0, out, N, T);
}

// Round 3
// 594.604 us; speedup vs baseline: 1.3960x; 1.0436x over previous
//
#include <hip/hip_runtime.h>
#include <math.h>

#define BLOCK 192   // wave 0 = compute (1 particle/lane), waves 1-2 = LDS->HBM writers
#define PPB   64    // particles per block
#define TW    16    // timesteps per LDS tile
#define ROW   385   // dwords per time-row: 6*64 + 1 (odd stride => conflict-free)
#define BUFSZ (TW * ROW)

// cos(2*pi*x) via native v_cos (input in revolutions); fract for exact periodic
// range reduction (handles slightly-negative z too).
#if defined(__has_builtin)
# if __has_builtin(__builtin_amdgcn_cosf) && __has_builtin(__builtin_amdgcn_fractf)
#  define COS2PI(x) __builtin_amdgcn_cosf(__builtin_amdgcn_fractf(x))
# endif
#endif
#ifndef COS2PI
# define COS2PI(x) __cosf(6.283185307179586f * (x))
#endif

// LDS layout: L[buf*BUFSZ + tt*ROW + c6*64 + pi(p)],  pi(p) = ((p&3)<<4)|(p>>2).
// Compute-side writes: 2 lanes/bank (free). Writer-side reads: lane=(g,e) reads
// 16 contiguous dwords at e*ROW + c6*64 + g*16 (bank = e+16g+i mod 32, 2-way, free),
// batched in flight. Global stores: 16 lanes cover 16 consecutive t per particle.
//
// Physics: B = [0, B0 cos(2 pi z), 0] => dp/dt _|_ p, so |p| (and gamma) is
// conserved exactly by the continuous dynamics and to O(dt^2 |dp|^2/|p|^2) ~ 2e-9
// per RK4 stage by the discrete one. We therefore hoist ig = 1/gamma out of the
// time loop, which removes all four rsqrt from the loop-carried dependency chain
// (the serial-chain floor this kernel is bound by). beta = p * (ig/c).
__global__ __launch_bounds__(BLOCK) void track_rk4(
    const float* __restrict__ r_in,
    const float* __restrict__ d_vec,
    const float* __restrict__ g_in,
    const float* __restrict__ t_in,
    const float* __restrict__ b_in,
    float* __restrict__ out,
    int N, int T)
{
    __shared__ float L[2 * BUFSZ];   // 49280 B

    const int tid    = threadIdx.x;
    const int wid    = tid >> 6;
    const int lane   = tid & 63;
    const int blockP = blockIdx.x * PPB;

    const long Tl     = (long)T;
    const long boff   = 3L * (long)N * Tl;
    const int  ntiles = (T + TW - 1) / TW;

    const float c      = 0.299792458f;
    const float inv_c2 = 1.0f / (c * c);
    const float inv_c  = 1.0f / c;

    const float b0  = b_in[0];
    const float dt  = t_in[1] - t_in[0];
    const float dt2 = 0.5f * dt;
    const float dt6 = dt * (1.0f / 6.0f);

    if (wid == 0) {
        // ======================= COMPUTE WAVE =======================
        float rx = 0.f, ry = 0.f, rz = 0.f, px = 0.f, py = 0.f, pz = 0.f;
        const int n0 = blockP + lane;
        if (n0 < N) {
            rx = r_in[3*n0+0]; ry = r_in[3*n0+1]; rz = r_in[3*n0+2];
            const float dx = d_vec[3*n0+0], dy = d_vec[3*n0+1], dz = d_vec[3*n0+2];
            const float g0 = g_in[n0];
            const float pscale = c * sqrtf(g0*g0 - 1.0f)
                               * rsqrtf(fmaf(dx,dx, fmaf(dy,dy, dz*dz)));
            px = dx * pscale; py = dy * pscale; pz = dz * pscale;
        }

        // ---- per-particle constants (gamma conserved: see header comment)
        const float p2s    = fmaf(px,px, fmaf(py,py, pz*pz));
        const float ig     = rsqrtf(fmaf(p2s, inv_c2, 1.0f));  // 1/gamma
        const float igdt2  = ig * dt2;
        const float igdt   = ig * dt;
        const float bigdt2 = b0 * igdt2;      // folds b0 into the force scale
        const float igdt6  = ig * dt6;
        const float dry    = py * igdt;       // exact per-step ry increment
        const float bscale = ig * inv_c;      // beta = p * bscale
        const float byv    = py * bscale;     // constant beta_y

        float cy = COS2PI(rz);                // raw cos(2 pi z) at current state

        const int pi = ((lane & 3) << 4) | (lane >> 2);

        for (int tile = 0; tile <= ntiles; ++tile) {
            if (tile < ntiles) {
                float* __restrict__ Lw = &L[(tile & 1) * BUFSZ + pi];
                const int t0 = tile * TW;
                #pragma unroll
                for (int tt = 0; tt < TW; ++tt) {
                    const int tg = t0 + tt;
                    if (tg < T) {
                        if (tg > 0) {
                            // ---- RK4 step, const-gamma form.
                            // g_i = By_i*ig*dt2 ; q_i = p_i (x|z) * g_i = |pk_i|*dt2
                            const float g1  = cy * bigdt2;
                            const float z2  = fmaf(pz, igdt2, rz);   // off-chain early
                            const float c2v = COS2PI(z2);
                            const float q1x = pz * g1;
                            const float q1z = px * g1;
                            const float p2x = px + q1x;
                            const float p2z = pz - q1z;

                            const float g2  = c2v * bigdt2;
                            const float z3  = fmaf(p2z, igdt2, rz);
                            const float c3v = COS2PI(z3);
                            const float q2x = p2z * g2;
                            const float q2z = p2x * g2;
                            const float p3x = px + q2x;
                            const float p3z = pz - q2z;

                            const float g3  = c3v * bigdt2;
                            const float z4  = fmaf(p3z, igdt, rz);
                            const float c4v = COS2PI(z4);
                            const float q3x = p3z * g3;
                            const float q3z = p3x * g3;
                            const float p4x = fmaf(q3x,  2.0f, px);
                            const float p4z = fmaf(q3z, -2.0f, pz);

                            const float g4  = c4v * bigdt2;
                            const float q4x = p4z * g4;
                            const float q4z = p4x * g4;

                            // r update: rx += dt6*ig*(px + 2 p2x + 2 p3x + p4x)
                            const float ax = px + p4x, bx = p2x + p3x;
                            const float az = pz + p4z, bz = p2z + p3z;
                            rx = fmaf(fmaf(bx, 2.0f, ax), igdt6, rx);
                            rz = fmaf(fmaf(bz, 2.0f, az), igdt6, rz);
                            ry += dry;

                            // p update: px += (q1+2q2+2q3+q4)/3 ; pz -= (...)/3
                            const float sx = q1x + q4x, tx = q2x + q3x;
                            const float sz = q1z + q4z, tz = q2z + q3z;
                            px = fmaf(fmaf(tx, 2.0f, sx),  (1.0f/3.0f), px);
                            pz = fmaf(fmaf(tz, 2.0f, sz), (-1.0f/3.0f), pz);

                            cy = COS2PI(rz);   // next step's stage-1 field
                        }
                        Lw[tt*ROW + 0*64] = rx;
                        Lw[tt*ROW + 1*64] = ry;
                        Lw[tt*ROW + 2*64] = rz;
                        Lw[tt*ROW + 3*64] = px * bscale;
                        Lw[tt*ROW + 4*64] = byv;
                        Lw[tt*ROW + 5*64] = pz * bscale;
                    }
                }
            }
            __syncthreads();
        }
    } else {
        // ======================= WRITER WAVES =======================
        // wave 1 drains c6 in {0,1,2}; wave 2 drains c6 in {3,4,5}
        const int g = lane >> 4;           // particle%4 slot
        const int e = lane & 15;           // time element within tile
        const int c6base = 3 * (wid - 1);
        const int rbase  = e * ROW + c6base * 64 + g * 16;
        const long pstride = 3L * Tl;      // +1 particle (same comp) in floats

        float* bp[3];
        #pragma unroll
        for (int j = 0; j < 3; ++j) {
            const int  c6  = c6base + j;
            const int  c6m = (c6 < 3) ? c6 : c6 - 3;
            const long sel = (c6 < 3) ? 0L : boff;
            bp[j] = out + sel + (3L*(blockP + g) + c6m) * Tl + e;
        }
        const int pbmax = N - blockP - g;  // store iff pb < pbmax

        for (int tile = 0; tile <= ntiles; ++tile) {
            if (tile > 0) {
                const int dtile = tile - 1;
                const float* __restrict__ Lb = &L[(dtile & 1) * BUFSZ];
                const int t0  = dtile * TW;
                const int rem = (T - t0 < TW) ? (T - t0) : TW;
                const bool on = (e < rem);
                #pragma unroll
                for (int j = 0; j < 3; ++j) {
                    float v[16];
                    #pragma unroll
                    for (int i = 0; i < 16; ++i)          // 16 contiguous dwords,
                        v[i] = Lb[rbase + j*64 + i];      // batched, conflict-free
                    #pragma unroll
                    for (int i = 0; i < 16; ++i) {
                        const int pb = i * 4;
                        if (on && pb < pbmax)
                            bp[j][(long)t0 + pb * pstride] = v[i];
                    }
                }
            }
            __syncthreads();
        }
    }
}

extern "C" void kernel_launch(void* const* d_in, const int* in_sizes, int n_in,
                              void* d_out, int out_size, void* d_ws, size_t ws_size,
                              hipStream_t stream) {
    const float* r  = (const float*)d_in[0];
    const float* d  = (const float*)d_in[1];
    const float* g  = (const float*)d_in[2];
    const float* tm = (const float*)d_in[3];
    const float* b0 = (const float*)d_in[4];
    float* out = (float*)d_out;

    const int N = in_sizes[2];   // bunch_gamma has N elements
    const int T = in_sizes[3];   // time has T elements

    const int blocks = (N + PPB - 1) / PPB;
    track_rk4<<<blocks, BLOCK, 0, stream>>>(r, d, g, tm, b0, out, N, T);
}